// Round 7
// baseline (595.279 us; speedup 1.0000x reference)
//
#include <hip/hip_runtime.h>
#include <cstdint>
#include <cstddef>

// Problem constants (B,T,C,H,D) = (4,2048,1024,16,64)
#define Bz 4
#define Tz 2048
#define Cz 1024
#define Hz 16
#define Dz 64
#define NTOK (Bz*Tz)   // 8192 tokens
#define CHL 32         // chunk length
#define NCH (Tz/CHL)   // 64 chunks per chain

typedef __attribute__((ext_vector_type(8))) short  short8;   // 8 x bf16 (4 VGPRs)
typedef __attribute__((ext_vector_type(4))) float  floatx4;  // MFMA accum

__device__ __forceinline__ unsigned short f2bf(float x) {
  union { float f; uint32_t u; } a; a.f = x;
  uint32_t r = a.u + 0x7fffu + ((a.u >> 16) & 1u);
  return (unsigned short)(r >> 16);
}
__device__ __forceinline__ float bf2f(unsigned short u) {
  union { uint32_t i; float f; } a; a.i = ((uint32_t)u) << 16; return a.f;
}
__device__ __forceinline__ float sigmoidf_(float z) {
  return 1.0f / (1.0f + __expf(-z));
}

// ---- DPP 16-lane row reduction ----
template<int CTRL>
__device__ __forceinline__ float dpp_addf(float x) {
  int y = __builtin_amdgcn_update_dpp(0, __float_as_int(x), CTRL, 0xF, 0xF, true);
  return x + __int_as_float(y);
}
__device__ __forceinline__ float rowsum16(float x) {
  x = dpp_addf<0xB1>(x);   // quad_perm xor1
  x = dpp_addf<0x4E>(x);   // quad_perm xor2
  x = dpp_addf<0x124>(x);  // row_ror:4
  x = dpp_addf<0x128>(x);  // row_ror:8
  return x;
}

union FragU { uint32_t u[4]; short8 s; };

// ---------------- fp32 -> bf16 converts ----------------
__global__ __launch_bounds__(256) void cvt_bf16_kernel(const float* __restrict__ in,
                                                       unsigned short* __restrict__ out,
                                                       int n4) {
  int i = blockIdx.x * blockDim.x + threadIdx.x;
  int stride = gridDim.x * blockDim.x;
  const float4* in4 = (const float4*)in;
  ushort4* out4 = (ushort4*)out;
  for (; i < n4; i += stride) {
    float4 f = in4[i];
    ushort4 u;
    u.x = f2bf(f.x); u.y = f2bf(f.y); u.z = f2bf(f.z); u.w = f2bf(f.w);
    out4[i] = u;
  }
}

__global__ __launch_bounds__(256) void cvt_w5_kernel(
    const float* __restrict__ s0, const float* __restrict__ s1,
    const float* __restrict__ s2, const float* __restrict__ s3,
    const float* __restrict__ s4,
    unsigned short* __restrict__ d0, unsigned short* __restrict__ d1,
    unsigned short* __restrict__ d2, unsigned short* __restrict__ d3,
    unsigned short* __restrict__ d4, int n4)
{
  const int w = blockIdx.y;
  const float* s = (w == 0) ? s0 : (w == 1) ? s1 : (w == 2) ? s2 : (w == 3) ? s3 : s4;
  unsigned short* d = (w == 0) ? d0 : (w == 1) ? d1 : (w == 2) ? d2 : (w == 3) ? d3 : d4;
  int i = blockIdx.x * blockDim.x + threadIdx.x;
  if (i < n4) {
    float4 f = ((const float4*)s)[i];
    ushort4 u;
    u.x = f2bf(f.x); u.y = f2bf(f.y); u.z = f2bf(f.z); u.w = f2bf(f.w);
    ((ushort4*)d)[i] = u;
  }
}

// ---------------- bf16 MFMA GEMM, DIRECT-REGISTER (no LDS, no barriers) --------
// C[m,n] = sum_k A[m,k]*B[n,k]; operands are L1/L2-resident at this shape, so
// each lane loads its MFMA fragment straight from global as one uint4:
// lanes (ml,kq) of a wave touch 16 lines of 64 B per instruction (coalesced).
// No __syncthreads -> compiler software-pipelines loads across K freely.
// norm_mask bit z: per-64-col (per-head) l2 normalization; out_bf16: bf16 store.
__global__ __launch_bounds__(256) void gemm_bt_kernel(
    const unsigned short* __restrict__ A,
    const unsigned short* __restrict__ W0, const unsigned short* __restrict__ W1,
    const unsigned short* __restrict__ W2, const unsigned short* __restrict__ W3,
    void* __restrict__ O0, void* __restrict__ O1,
    void* __restrict__ O2, void* __restrict__ O3,
    int M, int N, int K, int nz_sigmoid, int norm_mask, int out_bf16)
{
  const int z = blockIdx.z;
  const unsigned short* Bw = (z == 0) ? W0 : (z == 1) ? W1 : (z == 2) ? W2 : W3;
  void* Cw = (z == 0) ? O0 : (z == 1) ? O1 : (z == 2) ? O2 : O3;
  const bool act = (z == nz_sigmoid);
  const bool donorm = (norm_mask >> z) & 1;

  const int tid  = threadIdx.x;
  const int wid  = tid >> 6;
  const int lane = tid & 63;
  const int wm = wid & 1, wn = wid >> 1;   // waves (0,2) share A rows; (0,1) share B
  const int ml = lane & 15;
  const int kq = lane >> 4;
  const int m0 = blockIdx.y * 128;
  const int n0 = blockIdx.x * 128;

  const unsigned short* Ab = A  + (size_t)(m0 + wm * 64 + ml) * K + kq * 8;
  const unsigned short* Bb = Bw + (size_t)(n0 + wn * 64 + ml) * K + kq * 8;

  floatx4 acc[4][4];
#pragma unroll
  for (int i = 0; i < 4; ++i)
#pragma unroll
    for (int j = 0; j < 4; ++j)
      acc[i][j] = floatx4{0.f, 0.f, 0.f, 0.f};

#pragma unroll 2
  for (int kt = 0; kt < K; kt += 32) {
    FragU af[4], bfv[4];
#pragma unroll
    for (int i = 0; i < 4; ++i)
      *(uint4*)af[i].u = *(const uint4*)(Ab + (size_t)i * 16 * K + kt);
#pragma unroll
    for (int j = 0; j < 4; ++j)
      *(uint4*)bfv[j].u = *(const uint4*)(Bb + (size_t)j * 16 * K + kt);
#pragma unroll
    for (int i = 0; i < 4; ++i)
#pragma unroll
      for (int j = 0; j < 4; ++j)
        acc[i][j] = __builtin_amdgcn_mfma_f32_16x16x32_bf16(af[i].s, bfv[j].s, acc[i][j], 0, 0, 0);
  }

  float scale[4][4];
  if (donorm) {
#pragma unroll
    for (int i = 0; i < 4; ++i) {
#pragma unroll
      for (int r = 0; r < 4; ++r) {
        float ss = 0.f;
#pragma unroll
        for (int j = 0; j < 4; ++j) ss = fmaf(acc[i][j][r], acc[i][j][r], ss);
        ss = rowsum16(ss);
        scale[i][r] = 1.0f / fmaxf(sqrtf(ss), 1e-12f);
      }
    }
  }

  const int row_base = m0 + wm * 64;
  const int col_base = n0 + wn * 64;
#pragma unroll
  for (int i = 0; i < 4; ++i) {
#pragma unroll
    for (int j = 0; j < 4; ++j) {
      int col = col_base + j * 16 + ml;
#pragma unroll
      for (int r = 0; r < 4; ++r) {
        int row = row_base + i * 16 + kq * 4 + r;
        float val = acc[i][j][r];
        if (donorm) val *= scale[i][r];
        if (act) val = sigmoidf_(val);
        if (out_bf16) ((unsigned short*)Cw)[(size_t)row * N + col] = f2bf(val);
        else          ((float*)Cw)[(size_t)row * N + col] = val;
      }
    }
  }
}

// ---------------- beta projection (fp32, exact) ----------------
__global__ __launch_bounds__(256) void beta_kernel(
    const float* __restrict__ x, const float* __restrict__ Wb,
    const float* __restrict__ bb, float* __restrict__ beta_out)
{
  const int n = blockIdx.x;
  const int wid = threadIdx.x >> 6;
  const int lane = threadIdx.x & 63;
  const float* xr = x + (size_t)n * Cz;
  for (int h = wid; h < Hz; h += 4) {
    const float* wr = Wb + (size_t)h * Cz;
    float s = 0.f;
#pragma unroll 4
    for (int i = lane; i < Cz; i += 64) s = fmaf(xr[i], wr[i], s);
#pragma unroll
    for (int ofs = 32; ofs >= 1; ofs >>= 1) s += __shfl_xor(s, ofs);
    if (lane == 0) beta_out[(size_t)n * Hz + h] = sigmoidf_(s + bb[h]);
  }
}

// ======== Chunked delta rule (unchanged from R6) ========
__global__ __launch_bounds__(256) void deltachunk_phase1(
    const unsigned short* __restrict__ qb, const unsigned short* __restrict__ kb,
    const unsigned short* __restrict__ vb, const float* __restrict__ betaf,
    float* __restrict__ of,
    unsigned short* __restrict__ qtb, unsigned short* __restrict__ wbuf,
    unsigned short* __restrict__ ubuf, unsigned short* __restrict__ ktb)
{
  __shared__ unsigned short Kb[32][72], Qb[32][72], Vb[32][72];
  __shared__ float As[32][33];
  __shared__ unsigned short Sb[32][40];
  __shared__ unsigned short Us[32][72], Ws[32][72], Qts[32][72];
  __shared__ float bsh[32];

  const int bid = blockIdx.x;
  const int chain = bid & 63;          // chunk-major dispatch for L2 locality
  const int chunk = bid >> 6;
  const int b = chain >> 4, h = chain & 15;
  const int tid = threadIdx.x;
  const int wid = tid >> 6, lane = tid & 63;
  const int ml = lane & 15, kq = lane >> 4;

  const size_t tok0 = (size_t)b * Tz + (size_t)chunk * CHL;
  const size_t cb = ((size_t)chain * NCH + chunk) * 2048;  // compact base (u16)

  {
    const int row = tid >> 3, c8 = (tid & 7) * 8;
    const size_t ga = (tok0 + row) * Cz + h * Dz + c8;
    *(uint4*)&Qb[row][c8] = *(const uint4*)&qb[ga];
    *(uint4*)&Kb[row][c8] = *(const uint4*)&kb[ga];
    *(uint4*)&Vb[row][c8] = *(const uint4*)&vb[ga];
  }
  if (tid < 32) bsh[tid] = betaf[(tok0 + tid) * Hz + h];
  __syncthreads();

  {
    const int tr = wid & 1, tc = wid >> 1;
    floatx4 accA = {0.f,0.f,0.f,0.f}, accS = {0.f,0.f,0.f,0.f};
#pragma unroll
    for (int eh = 0; eh < 2; ++eh) {
      short8 ka = *(const short8*)&Kb[tr * 16 + ml][eh * 32 + kq * 8];
      short8 kbf = *(const short8*)&Kb[tc * 16 + ml][eh * 32 + kq * 8];
      short8 qa = *(const short8*)&Qb[tr * 16 + ml][eh * 32 + kq * 8];
      accA = __builtin_amdgcn_mfma_f32_16x16x32_bf16(ka, kbf, accA, 0, 0, 0);
      accS = __builtin_amdgcn_mfma_f32_16x16x32_bf16(qa, kbf, accS, 0, 0, 0);
    }
#pragma unroll
    for (int r = 0; r < 4; ++r) {
      int t = tr * 16 + kq * 4 + r;
      int s = tc * 16 + ml;
      As[t][s] = bsh[t] * accA[r];
      Sb[t][s] = (t > s) ? f2bf(accS[r]) : (unsigned short)0;
    }
  }
  __syncthreads();

  if (tid < 128) {
    const int j = tid;
    float x[32];
    if (j < 64) {
#pragma unroll
      for (int t = 0; t < 32; ++t) x[t] = bsh[t] * bf2f(Vb[t][j]);
    } else {
#pragma unroll
      for (int t = 0; t < 32; ++t) x[t] = bsh[t] * bf2f(Kb[t][j - 64]);
    }
#pragma unroll
    for (int t = 0; t < 31; ++t) {
      float xt = x[t];
#pragma unroll
      for (int s = t + 1; s < 32; ++s) x[s] = fmaf(-As[s][t], xt, x[s]);
    }
    if (j < 64) {
#pragma unroll
      for (int t = 0; t < 32; ++t) Us[t][j] = f2bf(x[t]);
    } else {
#pragma unroll
      for (int t = 0; t < 32; ++t) Ws[t][j - 64] = f2bf(x[t]);
    }
  }
  __syncthreads();

  {
    const int dw = wid * 16 + ml;
    FragU bu, bw;
#pragma unroll
    for (int r = 0; r < 4; ++r) {
      bu.u[r] = (uint32_t)Us[kq * 8 + 2 * r][dw] | ((uint32_t)Us[kq * 8 + 2 * r + 1][dw] << 16);
      bw.u[r] = (uint32_t)Ws[kq * 8 + 2 * r][dw] | ((uint32_t)Ws[kq * 8 + 2 * r + 1][dw] << 16);
    }
    floatx4 accO[2], accQ[2];
#pragma unroll
    for (int tt = 0; tt < 2; ++tt) { accO[tt] = floatx4{0.f,0.f,0.f,0.f}; accQ[tt] = floatx4{0.f,0.f,0.f,0.f}; }
#pragma unroll
    for (int tt = 0; tt < 2; ++tt) {
      short8 sa = *(const short8*)&Sb[tt * 16 + ml][kq * 8];
      accO[tt] = __builtin_amdgcn_mfma_f32_16x16x32_bf16(sa, bu.s, accO[tt], 0, 0, 0);
      accQ[tt] = __builtin_amdgcn_mfma_f32_16x16x32_bf16(sa, bw.s, accQ[tt], 0, 0, 0);
    }
#pragma unroll
    for (int tt = 0; tt < 2; ++tt) {
#pragma unroll
      for (int r = 0; r < 4; ++r) {
        int t = tt * 16 + kq * 4 + r;
        of[(tok0 + t) * Cz + h * Dz + dw] = accO[tt][r];
        Qts[t][dw] = f2bf(bf2f(Qb[t][dw]) - accQ[tt][r]);
      }
    }
  }

  unsigned short ktmp[8];
  {
    const int e = tid >> 2, tq = (tid & 3) * 8;
#pragma unroll
    for (int i2 = 0; i2 < 8; ++i2) ktmp[i2] = Kb[tq + i2][e];
  }
  __syncthreads();

  {
    const int row = tid >> 3, c8 = (tid & 7) * 8;
    const size_t o16 = cb + (size_t)row * 64 + c8;
    *(uint4*)&qtb[o16]  = *(const uint4*)&Qts[row][c8];
    *(uint4*)&wbuf[o16] = *(const uint4*)&Ws[row][c8];
    *(uint4*)&ubuf[o16] = *(const uint4*)&Us[row][c8];
    const int e = tid >> 2, tq = (tid & 3) * 8;
    *(uint4*)&ktb[cb + (size_t)e * 32 + tq] = *(const uint4*)ktmp;
  }
}

__global__ __launch_bounds__(256) void deltachunk_phase2(
    const unsigned short* __restrict__ qtb, const unsigned short* __restrict__ wbuf,
    const unsigned short* __restrict__ ubuf, const unsigned short* __restrict__ ktb,
    float* __restrict__ of)
{
  __shared__ unsigned short Gb[64][72];    // rows 0..31 Qt, 32..63 W  [i][e]
  __shared__ unsigned short Kts[64][40];   // [e][t]
  __shared__ unsigned short Ub[32][72];    // [t][d]
  __shared__ unsigned short Mh[64][72], Ml[64][72];   // [d][e] hi/lo
  __shared__ unsigned short Zh[64][40], Zl[64][40];   // [d][t] hi/lo

  const int chain = blockIdx.x;
  const int b = chain >> 4, h = chain & 15;
  const int tid = threadIdx.x;
  const int wid = tid >> 6, lane = tid & 63;
  const int ml = lane & 15, kq = lane >> 4;
  const int iq = wid >> 1, jq = wid & 1;
  const int dq = wid >> 1, eq = wid & 1;

  for (int i = tid; i < 64 * 72; i += 256) { (&Mh[0][0])[i] = 0; (&Ml[0][0])[i] = 0; }
  floatx4 mAcc[2][2];
#pragma unroll
  for (int a = 0; a < 2; ++a)
#pragma unroll
    for (int e = 0; e < 2; ++e) mAcc[a][e] = floatx4{0.f,0.f,0.f,0.f};

  const int grow = tid >> 3, gc8 = (tid & 7) * 8;
  const int ke = tid >> 2,  kt8 = (tid & 3) * 8;

  {
    const size_t cb = (size_t)chain * NCH * 2048;
    *(uint4*)&Gb[grow][gc8]      = *(const uint4*)&qtb[cb + (size_t)grow * 64 + gc8];
    *(uint4*)&Gb[32 + grow][gc8] = *(const uint4*)&wbuf[cb + (size_t)grow * 64 + gc8];
    *(uint4*)&Ub[grow][gc8]      = *(const uint4*)&ubuf[cb + (size_t)grow * 64 + gc8];
    *(uint4*)&Kts[ke][kt8]       = *(const uint4*)&ktb[cb + (size_t)ke * 32 + kt8];
  }
  __syncthreads();

  for (int c = 0; c < NCH; ++c) {
    const size_t tok0 = (size_t)b * Tz + (size_t)c * CHL;
    float pre[2][2][4];
    if (iq == 0) {
#pragma unroll
      for (int ti = 0; ti < 2; ++ti)
#pragma unroll
        for (int tj = 0; tj < 2; ++tj)
#pragma unroll
          for (int r = 0; r < 4; ++r)
            pre[ti][tj][r] = of[(tok0 + ti * 16 + kq * 4 + r) * Cz + h * Dz + jq * 32 + tj * 16 + ml];
    }
    const int cn = (c + 1 < NCH) ? c + 1 : c;
    const size_t cbn = ((size_t)chain * NCH + cn) * 2048;
    uint4 sq = *(const uint4*)&qtb[cbn + (size_t)grow * 64 + gc8];
    uint4 sw = *(const uint4*)&wbuf[cbn + (size_t)grow * 64 + gc8];
    uint4 su = *(const uint4*)&ubuf[cbn + (size_t)grow * 64 + gc8];
    uint4 sk = *(const uint4*)&ktb[cbn + (size_t)ke * 32 + kt8];

    __syncthreads();

    floatx4 g1[2][2];
#pragma unroll
    for (int ti = 0; ti < 2; ++ti)
#pragma unroll
      for (int tj = 0; tj < 2; ++tj) g1[ti][tj] = floatx4{0.f,0.f,0.f,0.f};
#pragma unroll
    for (int eh = 0; eh < 2; ++eh) {
      short8 afr[2];
      afr[0] = *(const short8*)&Gb[iq * 32 + 0  + ml][eh * 32 + kq * 8];
      afr[1] = *(const short8*)&Gb[iq * 32 + 16 + ml][eh * 32 + kq * 8];
#pragma unroll
      for (int hl = 0; hl < 2; ++hl) {
#pragma unroll
        for (int tj = 0; tj < 2; ++tj) {
          short8 bfr = hl ? *(const short8*)&Ml[jq * 32 + tj * 16 + ml][eh * 32 + kq * 8]
                          : *(const short8*)&Mh[jq * 32 + tj * 16 + ml][eh * 32 + kq * 8];
          g1[0][tj] = __builtin_amdgcn_mfma_f32_16x16x32_bf16(afr[0], bfr, g1[0][tj], 0, 0, 0);
          g1[1][tj] = __builtin_amdgcn_mfma_f32_16x16x32_bf16(afr[1], bfr, g1[1][tj], 0, 0, 0);
        }
      }
    }
    if (iq == 0) {
#pragma unroll
      for (int ti = 0; ti < 2; ++ti)
#pragma unroll
        for (int tj = 0; tj < 2; ++tj)
#pragma unroll
          for (int r = 0; r < 4; ++r)
            of[(tok0 + ti * 16 + kq * 4 + r) * Cz + h * Dz + jq * 32 + tj * 16 + ml] =
                pre[ti][tj][r] + g1[ti][tj][r];
    } else {
#pragma unroll
      for (int ti = 0; ti < 2; ++ti)
#pragma unroll
        for (int tj = 0; tj < 2; ++tj)
#pragma unroll
          for (int r = 0; r < 4; ++r) {
            int t = ti * 16 + kq * 4 + r, d = jq * 32 + tj * 16 + ml;
            float z = bf2f(Ub[t][d]) - g1[ti][tj][r];
            unsigned short zh = f2bf(z);
            Zh[d][t] = zh;
            Zl[d][t] = f2bf(z - bf2f(zh));
          }
    }
    __syncthreads();

    {
      short8 kfr[2];
      kfr[0] = *(const short8*)&Kts[eq * 32 + 0  + ml][kq * 8];
      kfr[1] = *(const short8*)&Kts[eq * 32 + 16 + ml][kq * 8];
#pragma unroll
      for (int hl = 0; hl < 2; ++hl) {
#pragma unroll
        for (int dt = 0; dt < 2; ++dt) {
          short8 afr = hl ? *(const short8*)&Zl[dq * 32 + dt * 16 + ml][kq * 8]
                          : *(const short8*)&Zh[dq * 32 + dt * 16 + ml][kq * 8];
          mAcc[dt][0] = __builtin_amdgcn_mfma_f32_16x16x32_bf16(afr, kfr[0], mAcc[dt][0], 0, 0, 0);
          mAcc[dt][1] = __builtin_amdgcn_mfma_f32_16x16x32_bf16(afr, kfr[1], mAcc[dt][1], 0, 0, 0);
        }
      }
#pragma unroll
      for (int dt = 0; dt < 2; ++dt)
#pragma unroll
        for (int et = 0; et < 2; ++et)
#pragma unroll
          for (int r = 0; r < 4; ++r) {
            int d = dq * 32 + dt * 16 + kq * 4 + r;
            int ec = eq * 32 + et * 16 + ml;
            float mv = mAcc[dt][et][r];
            unsigned short mh = f2bf(mv);
            Mh[d][ec] = mh;
            Ml[d][ec] = f2bf(mv - bf2f(mh));
          }
    }
    __syncthreads();

    *(uint4*)&Gb[grow][gc8]      = sq;
    *(uint4*)&Gb[32 + grow][gc8] = sw;
    *(uint4*)&Ub[grow][gc8]      = su;
    *(uint4*)&Kts[ke][kt8]       = sk;
  }
}

// ---------------- gate*o -> bf16 ----------------
__global__ __launch_bounds__(256) void gate_mul_kernel(
    const unsigned short* __restrict__ gsig, const float* __restrict__ o,
    unsigned short* __restrict__ out, int n4)
{
  int i = blockIdx.x * blockDim.x + threadIdx.x;
  int stride = gridDim.x * blockDim.x;
  const ushort4* g4 = (const ushort4*)gsig;
  const float4* o4 = (const float4*)o;
  ushort4* out4 = (ushort4*)out;
  for (; i < n4; i += stride) {
    ushort4 gv = g4[i];
    float4 ov = o4[i];
    ushort4 u;
    u.x = f2bf(bf2f(gv.x) * ov.x);
    u.y = f2bf(bf2f(gv.y) * ov.y);
    u.z = f2bf(bf2f(gv.z) * ov.z);
    u.w = f2bf(bf2f(gv.w) * ov.w);
    out4[i] = u;
  }
}

extern "C" void kernel_launch(void* const* d_in, const int* in_sizes, int n_in,
                              void* d_out, int out_size, void* d_ws, size_t ws_size,
                              hipStream_t stream) {
  const float* x     = (const float*)d_in[0];
  const float* Wq    = (const float*)d_in[1];
  const float* Wk    = (const float*)d_in[2];
  const float* Wv    = (const float*)d_in[3];
  const float* Wbeta = (const float*)d_in[4];
  const float* bbeta = (const float*)d_in[5];
  const float* Wgate = (const float*)d_in[6];
  const float* Wo    = (const float*)d_in[7];
  float* out = (float*)d_out;

  char* ws = (char*)d_ws;
  size_t off = 0;
  auto alloc = [&](size_t bytes) -> char* {
    char* p = ws + off;
    off += (bytes + 255) & ~(size_t)255;
    return p;
  };
  unsigned short* xb  = (unsigned short*)alloc((size_t)NTOK * Cz * 2);
  unsigned short* Wqb = (unsigned short*)alloc((size_t)Cz * Cz * 2);
  unsigned short* Wkb = (unsigned short*)alloc((size_t)Cz * Cz * 2);
  unsigned short* Wvb = (unsigned short*)alloc((size_t)Cz * Cz * 2);
  unsigned short* Wgb = (unsigned short*)alloc((size_t)Cz * Cz * 2);
  unsigned short* Wob = (unsigned short*)alloc((size_t)Cz * Cz * 2);
  unsigned short* qb  = (unsigned short*)alloc((size_t)NTOK * Cz * 2);
  unsigned short* kb  = (unsigned short*)alloc((size_t)NTOK * Cz * 2);
  unsigned short* vb  = (unsigned short*)alloc((size_t)NTOK * Cz * 2);
  unsigned short* gb  = (unsigned short*)alloc((size_t)NTOK * Cz * 2);
  float* of    = (float*)alloc((size_t)NTOK * Cz * 4);
  float* betaf = (float*)alloc((size_t)NTOK * Hz * 4);
  unsigned short* qtb  = (unsigned short*)alloc((size_t)64 * NCH * 2048 * 2);
  unsigned short* wbuf = (unsigned short*)alloc((size_t)64 * NCH * 2048 * 2);
  unsigned short* ubuf = (unsigned short*)alloc((size_t)64 * NCH * 2048 * 2);
  unsigned short* ktb  = (unsigned short*)alloc((size_t)64 * NCH * 2048 * 2);
  unsigned short* ab = xb;  // reuse xb after projection GEMMs

  const int n4x = NTOK * Cz / 4;
  const int n4w = Cz * Cz / 4;

  cvt_bf16_kernel<<<dim3(1024), dim3(256), 0, stream>>>(x, xb, n4x);
  cvt_w5_kernel<<<dim3(n4w / 256, 5), dim3(256), 0, stream>>>(
      Wq, Wk, Wv, Wgate, Wo, Wqb, Wkb, Wvb, Wgb, Wob, n4w);

  // fused q,k,v,gate projections -> bf16; q,k l2norm epilogue, gate sigmoid
  gemm_bt_kernel<<<dim3(Cz / 128, NTOK / 128, 4), dim3(256), 0, stream>>>(
      xb, Wqb, Wkb, Wvb, Wgb, qb, kb, vb, gb, NTOK, Cz, Cz, 3, 3, 1);

  beta_kernel<<<dim3(NTOK), dim3(256), 0, stream>>>(x, Wbeta, bbeta, betaf);

  deltachunk_phase1<<<dim3(64 * NCH), dim3(256), 0, stream>>>(
      qb, kb, vb, betaf, of, qtb, wbuf, ubuf, ktb);
  deltachunk_phase2<<<dim3(Bz * Hz), dim3(256), 0, stream>>>(qtb, wbuf, ubuf, ktb, of);

  gate_mul_kernel<<<dim3(1024), dim3(256), 0, stream>>>(gb, of, ab, n4x);

  // out = (gate*o) @ Wo^T  (fp32 output)
  gemm_bt_kernel<<<dim3(Cz / 128, NTOK / 128, 1), dim3(256), 0, stream>>>(
      ab, Wob, Wob, Wob, Wob, out, out, out, out, NTOK, Cz, Cz, -1, 0, 0);
}